// Round 7
// baseline (101.078 us; speedup 1.0000x reference)
//
#include <hip/hip_runtime.h>
#include <hip/hip_bf16.h>
#include <math.h>

constexpr int B = 2, N = 2048, D = 384, H = 8, Dh = 48;
constexpr int M = B * N;            // 4096 rows
constexpr float EPS = 1e-5f;
constexpr int WSZ = 384 * 384;

typedef short bf16x8 __attribute__((ext_vector_type(8)));
typedef short bf16x4 __attribute__((ext_vector_type(4)));
typedef float f32x4 __attribute__((ext_vector_type(4)));

#if __has_builtin(__builtin_amdgcn_exp2f)
#define EXP2(x) __builtin_amdgcn_exp2f(x)
#else
#define EXP2(x) exp2f(x)
#endif

#if __has_builtin(__builtin_amdgcn_mfma_f32_16x16x16bf16_1k)
#define HAVE_MFMA16 1
#define MFMA16(a, b, c) __builtin_amdgcn_mfma_f32_16x16x16bf16_1k(a, b, c, 0, 0, 0)
#else
#define HAVE_MFMA16 0
#endif

__device__ __forceinline__ ushort f2bf(float f) {
  union { float f; uint u; } v; v.f = f;
  uint r = v.u + 0x7fffu + ((v.u >> 16) & 1u);   // RNE
  return (ushort)(r >> 16);
}
__device__ __forceinline__ float bf2f(ushort u) {
  union { uint u; float f; } v; v.u = ((uint)u) << 16;
  return v.f;
}
// two f32 -> packed 2xbf16 (compiler emits v_cvt_pk_bf16_f32)
__device__ __forceinline__ uint pk_bf16(float lo, float hi) {
  union { __hip_bfloat162 h; uint u; } v;
  v.h = __float22bfloat162_rn(make_float2(lo, hi));
  return v.u;
}

// async 16B global->LDS (dest: wave-uniform base + lane*16; src: per-lane)
__device__ __forceinline__ void gload16(const void* g, void* lds) {
  __builtin_amdgcn_global_load_lds(
      (const __attribute__((address_space(1))) unsigned int*)g,
      (__attribute__((address_space(3))) unsigned int*)lds, 16, 0, 0);
}

// Pack x and all 4 weights to bf16 in one kernel. 8 f32 per thread.
__global__ __launch_bounds__(256) void pack_all(
    const float* __restrict__ x, const float* __restrict__ Wq,
    const float* __restrict__ Wk, const float* __restrict__ Wv,
    const float* __restrict__ Wo, ushort* __restrict__ xbf,
    ushort* __restrict__ Wqkv, ushort* __restrict__ Wobf) {
  constexpr int XSZ = M * 384;
  int i = (blockIdx.x * 256 + threadIdx.x) * 8;
  const float* src; ushort* dst; int off;
  if (i < XSZ) { src = x; dst = xbf; off = i; }
  else {
    int j = i - XSZ;
    if (j < WSZ)          { src = Wq; dst = Wqkv;           off = j; }
    else if (j < 2 * WSZ) { src = Wk; dst = Wqkv + WSZ;     off = j - WSZ; }
    else if (j < 3 * WSZ) { src = Wv; dst = Wqkv + 2 * WSZ; off = j - 2 * WSZ; }
    else                  { src = Wo; dst = Wobf;           off = j - 3 * WSZ; }
  }
  float4 a = *(const float4*)(src + off);
  float4 b = *(const float4*)(src + off + 4);
  uint4 o;
  o.x = pk_bf16(a.x, a.y);
  o.y = pk_bf16(a.z, a.w);
  o.z = pk_bf16(b.x, b.y);
  o.w = pk_bf16(b.z, b.w);
  *(uint4*)(dst + off) = o;
}

// Fused QKV GEMM: [4096 x 1152] = xbf * Wqkv^T, bf16 MFMA, 64x128 tiles.
// Q cols -> Qpad[bn][h*64+dh], K cols -> Kpad (same layout), V -> Vt[b][h][dh][n].
__global__ __launch_bounds__(256) void gemm_qkv(
    const ushort* __restrict__ Abf, const ushort* __restrict__ Wbf,
    ushort* __restrict__ Qpad, ushort* __restrict__ Kpad,
    ushort* __restrict__ Vt) {
  __shared__ ushort Asm[64 * 32];
  __shared__ ushort Bsm[128 * 32];
  const int tid = threadIdx.x, w = tid >> 6, lane = tid & 63;
  const int lq = lane & 15, g = lane >> 4;
  const int brow = blockIdx.y * 64, bcol = blockIdx.x * 128;
  const int wr0 = (w >> 1) * 32, wc0 = (w & 1) * 64;
  const int srow = lane >> 2, scol = (lane & 3) * 8;
  f32x4 acc[2][4];
#pragma unroll
  for (int mi = 0; mi < 2; ++mi)
#pragma unroll
    for (int ni = 0; ni < 4; ++ni) acc[mi][ni] = f32x4{0.f, 0.f, 0.f, 0.f};

  for (int kt = 0; kt < 384; kt += 32) {
    __syncthreads();
    gload16(Abf + (size_t)(brow + w * 16 + srow) * 384 + kt + scol, Asm + w * 512);
#pragma unroll
    for (int i = 0; i < 2; ++i) {
      int seg = w * 2 + i;
      gload16(Wbf + (size_t)(bcol + seg * 16 + srow) * 384 + kt + scol, Bsm + seg * 512);
    }
    __syncthreads();
    bf16x8 a[2], b[4];
#pragma unroll
    for (int mi = 0; mi < 2; ++mi)
      a[mi] = *(const bf16x8*)(Asm + (wr0 + mi * 16 + lq) * 32 + g * 8);
#pragma unroll
    for (int ni = 0; ni < 4; ++ni)
      b[ni] = *(const bf16x8*)(Bsm + (wc0 + ni * 16 + lq) * 32 + g * 8);
#pragma unroll
    for (int mi = 0; mi < 2; ++mi)
#pragma unroll
      for (int ni = 0; ni < 4; ++ni)
        acc[mi][ni] = __builtin_amdgcn_mfma_f32_16x16x32_bf16(a[mi], b[ni], acc[mi][ni], 0, 0, 0);
  }

  if (bcol < 768) {
#pragma unroll
    for (int mi = 0; mi < 2; ++mi)
#pragma unroll
      for (int ni = 0; ni < 4; ++ni) {
        int colD = bcol + wc0 + ni * 16 + lq;
        ushort* dstm = (colD < 384) ? Qpad : Kpad;
        int c = (colD < 384) ? colD : colD - 384;
        int hh = c / 48, dh = c - hh * 48;
#pragma unroll
        for (int r = 0; r < 4; ++r) {
          int row = brow + wr0 + mi * 16 + g * 4 + r;
          dstm[(size_t)row * 512 + hh * 64 + dh] = f2bf(acc[mi][ni][r]);
        }
      }
  } else {
#pragma unroll
    for (int mi = 0; mi < 2; ++mi)
#pragma unroll
      for (int ni = 0; ni < 4; ++ni) {
        int vcol = bcol + wc0 + ni * 16 + lq - 768;
        int hh = vcol / 48, dh = vcol - hh * 48;
#pragma unroll
        for (int r = 0; r < 4; ++r) {
          int row = brow + wr0 + mi * 16 + g * 4 + r;
          int bb = row >> 11, nn = row & 2047;
          Vt[((size_t)(bb * H + hh) * 48 + dh) * N + nn] = f2bf(acc[mi][ni][r]);
        }
      }
  }
}

// In-place rotate 3-vector chunks of Qpad (scaled) and Kpad; zero pad halves 48..63.
__global__ __launch_bounds__(256) void rotate_both(
    ushort* __restrict__ Q, ushort* __restrict__ K,
    const float* __restrict__ F, float qscale) {
  constexpr int TOT = M * H * 16;
  int idx = blockIdx.x * 256 + threadIdx.x;   // 2*TOT threads
  ushort* T = (idx < TOT) ? Q : K;
  float scale = (idx < TOT) ? qscale : 1.0f;
  int rem = (idx < TOT) ? idx : idx - TOT;
  int gq = rem & 15;
  int nh = rem >> 4;
  int h = nh & 7;
  int bn = nh >> 3;
  ushort* p = T + (size_t)bn * 512 + h * 64;
  if (gq < 8) *(uint*)(p + 48 + gq * 2) = 0u;    // zero padding halves 48..63
  ushort* s = p + gq * 3;
  const float* R = F + (size_t)bn * 9;
  float v0 = bf2f(s[0]), v1 = bf2f(s[1]), v2 = bf2f(s[2]);
  float w0 = (R[0] * v0 + R[1] * v1 + R[2] * v2) * scale;
  float w1 = (R[3] * v0 + R[4] * v1 + R[5] * v2) * scale;
  float w2 = (R[6] * v0 + R[7] * v1 + R[8] * v2) * scale;
  s[0] = f2bf(w0); s[1] = f2bf(w1); s[2] = f2bf(w2);
}

// Wave-owns-keys split-K MFMA flash attention.
// Block = (half,b,h,qt): 64 q rows; wave w owns keys [w*16, w*16+16) of each
// staged 64-key tile. All 64 q live in registers as B-frags. Scores feed PV
// directly (mfma 16x16x16: D row-slice == A k-slice) -> P never touches LDS.
// Cross-wave merge in LDS at end; writes unnormalized bf16 acc + f32 (m,l).
__global__ __launch_bounds__(256) void attn_mfma(
    const ushort* __restrict__ Qpad, const ushort* __restrict__ Kpad,
    const ushort* __restrict__ Vt, ushort* __restrict__ Pacc,
    float* __restrict__ Pml) {
  __shared__ __align__(16) ushort SH[16384];   // 32KB
  ushort* Kb0 = SH;            // K dbuf: 2 x 64x64
  ushort* Kb1 = SH + 4096;
  ushort* Vb0 = SH + 8192;     // V dbuf: 2 x 48x64
  ushort* Vb1 = SH + 11264;
#if !HAVE_MFMA16
  ushort* Psc = SH + 14336;    // fallback: [4 waves][16 q][32 k]
#endif

  const int bid = blockIdx.x;
  const int wg = (bid & 7) * 128 + (bid >> 3);  // XCD swizzle (1024 = 8*128)
  const int qt = wg & 31;
  const int rest = wg >> 5;
  const int h = rest & 7;
  const int b = (rest >> 3) & 1;
  const int half = rest >> 4;
  const int kt0 = half * 1024;
  const int tid = threadIdx.x;
  const int w = tid >> 6;
  const int lane = tid & 63;
  const int lq = lane & 15;
  const int g = lane >> 4;
  const int srow8 = lane >> 3;                       // staging row within 8-row seg
  const int csw = (lane & 7) ^ srow8;                // K source 16B-block swizzle
  const int vsw = (lane & 7) ^ ((4 * (w & 1) + (srow8 >> 1)) & 7);  // V source

#if !HAVE_MFMA16
  if (g < 2) {  // zero P-scratch k-padding once
    uint4 z = make_uint4(0, 0, 0, 0);
    *(uint4*)(Psc + w * 512 + lq * 32 + 16 + g * 8) = z;
  }
#endif

  // All 64 q in registers as B-frags: qf[qg][ks] = Q[qg*16+lq][ks*32+g*8..+8]
  bf16x8 qf[4][2];
  {
    const ushort* qb = Qpad + (size_t)(b * N + qt * 64) * 512 + h * 64;
#pragma unroll
    for (int qg = 0; qg < 4; ++qg)
#pragma unroll
      for (int ks = 0; ks < 2; ++ks)
        qf[qg][ks] = *(const bf16x8*)(qb + (size_t)(qg * 16 + lq) * 512 + ks * 32 + g * 8);
  }

  const ushort* kg0 = Kpad + ((size_t)(b * N) + kt0 + w * 8 + srow8) * 512 + h * 64 + csw * 8;
  const ushort* kg1 = kg0 + 32 * 512;
  const ushort* vg0 = Vt + ((size_t)(b * H + h) * 48 + w * 8 + srow8) * (size_t)N + kt0 + vsw * 8;
  const ushort* vg1 = vg0 + 32 * (size_t)N;   // only issued when w<2

  auto stage = [&](ushort* kb, ushort* vb) {
    gload16(kg0, kb + w * 512);
    gload16(kg1, kb + (w + 4) * 512);
    gload16(vg0, vb + w * 512);
    if (w < 2) gload16(vg1, vb + (w + 4) * 512);
    kg0 += 64 * 512; kg1 += 64 * 512; vg0 += 64; vg1 += 64;
  };

  float m[4], l[4];
  f32x4 oacc[4][3];
#pragma unroll
  for (int qg = 0; qg < 4; ++qg) {
    m[qg] = -3.0e38f; l[qg] = 0.f;
#pragma unroll
    for (int d = 0; d < 3; ++d) oacc[qg][d] = f32x4{0.f, 0.f, 0.f, 0.f};
  }

  stage(Kb0, Vb0);
  __syncthreads();
  int cur = 0;

  for (int t = 0; t < 16; ++t) {
    if (t < 15) stage(cur ? Kb0 : Kb1, cur ? Vb0 : Vb1);
    const ushort* Kc = cur ? Kb1 : Kb0;
    const ushort* Vc = cur ? Vb1 : Vb0;

    // K frags for this wave's 16 keys (A-operand, reused across 4 q-groups)
    bf16x8 kf0 = *(const bf16x8*)(Kc + (w * 16 + lq) * 64 + ((g ^ (lq & 7)) * 8));
    bf16x8 kf1 = *(const bf16x8*)(Kc + (w * 16 + lq) * 64 + (((4 + g) ^ (lq & 7)) * 8));

    // S^T: st[qg][r] = S[key_local = g*4+r][q = qg*16+lq]
    f32x4 st[4];
#pragma unroll
    for (int qg = 0; qg < 4; ++qg) {
      st[qg] = f32x4{0.f, 0.f, 0.f, 0.f};
      st[qg] = __builtin_amdgcn_mfma_f32_16x16x32_bf16(kf0, qf[qg][0], st[qg], 0, 0, 0);
      st[qg] = __builtin_amdgcn_mfma_f32_16x16x32_bf16(kf1, qf[qg][1], st[qg], 0, 0, 0);
    }

    // V frags for PV (B-operand, reused across q-groups)
#if HAVE_MFMA16
    bf16x4 vb[3];
#pragma unroll
    for (int d = 0; d < 3; ++d)
      vb[d] = *(const bf16x4*)(Vc + (d * 16 + lq) * 64 + (((w * 4 + g) ^ (lq & 14)) * 4));
#endif

    // online softmax per q (wave-local keys)
    float tmax[4];
    bool need = false;
#pragma unroll
    for (int qg = 0; qg < 4; ++qg) {
      float t0 = fmaxf(fmaxf(st[qg][0], st[qg][1]), fmaxf(st[qg][2], st[qg][3]));
      t0 = fmaxf(t0, __shfl_xor(t0, 16));
      t0 = fmaxf(t0, __shfl_xor(t0, 32));
      tmax[qg] = t0;
      need |= (t0 > m[qg] + 8.0f);
    }
    if (__ballot(need)) {
#pragma unroll
      for (int qg = 0; qg < 4; ++qg) {
        float mnew = fmaxf(m[qg], tmax[qg]);
        float corr = EXP2(m[qg] - mnew);
        m[qg] = mnew;
        l[qg] *= corr;
#pragma unroll
        for (int r = 0; r < 4; ++r) {
          float cr = __shfl(corr, g * 4 + r);
#pragma unroll
          for (int d = 0; d < 3; ++d) oacc[qg][d][r] *= cr;
        }
      }
    }

#pragma unroll
    for (int qg = 0; qg < 4; ++qg) {
      float p0 = EXP2(st[qg][0] - m[qg]);
      float p1 = EXP2(st[qg][1] - m[qg]);
      float p2 = EXP2(st[qg][2] - m[qg]);
      float p3 = EXP2(st[qg][3] - m[qg]);
      float ps = (p0 + p1) + (p2 + p3);
      ps += __shfl_xor(ps, 16);
      ps += __shfl_xor(ps, 32);
      l[qg] += ps;
#if HAVE_MFMA16
      union { uint2 u; bf16x4 v; } pw;
      pw.u.x = pk_bf16(p0, p1);
      pw.u.y = pk_bf16(p2, p3);
#pragma unroll
      for (int d = 0; d < 3; ++d)
        oacc[qg][d] = MFMA16(pw.v, vb[d], oacc[qg][d]);
#else
      // fallback: bounce P through per-wave LDS, PV via 16x16x32 (upper k zero)
      uint2 pu; pu.x = pk_bf16(p0, p1); pu.y = pk_bf16(p2, p3);
      *(uint2*)(Psc + w * 512 + lq * 32 + g * 4) = pu;
      bf16x8 pf = *(const bf16x8*)(Psc + w * 512 + lq * 32 + g * 8);
#pragma unroll
      for (int d = 0; d < 3; ++d) {
        bf16x8 vf = *(const bf16x8*)(Vc + (d * 16 + lq) * 64 +
                                     (((w * 2 + g) ^ ((lq >> 1) & 7)) * 8));
        oacc[qg][d] = __builtin_amdgcn_mfma_f32_16x16x32_bf16(pf, vf, oacc[qg][d], 0, 0, 0);
      }
#endif
    }

    __syncthreads();   // drains staged loads for next tile; guards buffer reuse
    cur ^= 1;
  }

  // ---- cross-wave merge via LDS (waves own interleaved key subsets) ----
  uint2* Om = (uint2*)SH;                 // [(w'*4+qg)*3+d]*64 + g*16+lq : 24KB
  float2* Ml = (float2*)(SH + 12288);     // [(w'*4+qg)*16 + lq] : 2KB
#pragma unroll
  for (int qg = 0; qg < 4; ++qg)
#pragma unroll
    for (int d = 0; d < 3; ++d) {
      uint2 u;
      u.x = pk_bf16(oacc[qg][d][0], oacc[qg][d][1]);
      u.y = pk_bf16(oacc[qg][d][2], oacc[qg][d][3]);
      Om[((w * 4 + qg) * 3 + d) * 64 + g * 16 + lq] = u;
    }
  if (g == 0) {
#pragma unroll
    for (int qg = 0; qg < 4; ++qg)
      Ml[(w * 4 + qg) * 16 + lq] = make_float2(m[qg], l[qg]);
  }
  __syncthreads();

  // wave w outputs q = qt*64 + w*16 + g*4 + r ; dh = d*16 + lq
  float mp[4][4], lp[4][4];
#pragma unroll
  for (int wp = 0; wp < 4; ++wp)
#pragma unroll
    for (int r = 0; r < 4; ++r) {
      float2 t2 = Ml[(wp * 4 + w) * 16 + g * 4 + r];
      mp[wp][r] = t2.x; lp[wp][r] = t2.y;
    }
  float Mx[4], Lt[4], Wt[4][4];
#pragma unroll
  for (int r = 0; r < 4; ++r) {
    Mx[r] = fmaxf(fmaxf(mp[0][r], mp[1][r]), fmaxf(mp[2][r], mp[3][r]));
    Lt[r] = 0.f;
#pragma unroll
    for (int wp = 0; wp < 4; ++wp) {
      Wt[wp][r] = EXP2(mp[wp][r] - Mx[r]);
      Lt[r] += lp[wp][r] * Wt[wp][r];
    }
  }
  const size_t pr0 = ((size_t)((half * B + b) * H + h)) * N + qt * 64 + w * 16;
#pragma unroll
  for (int d = 0; d < 3; ++d) {
    float od[4] = {0.f, 0.f, 0.f, 0.f};
#pragma unroll
    for (int wp = 0; wp < 4; ++wp) {
      uint2 u = Om[((wp * 4 + w) * 3 + d) * 64 + g * 16 + lq];
      od[0] += bf2f((ushort)u.x) * Wt[wp][0];
      od[1] += bf2f((ushort)(u.x >> 16)) * Wt[wp][1];
      od[2] += bf2f((ushort)u.y) * Wt[wp][2];
      od[3] += bf2f((ushort)(u.y >> 16)) * Wt[wp][3];
    }
#pragma unroll
    for (int r = 0; r < 4; ++r)
      Pacc[(pr0 + g * 4 + r) * 48 + d * 16 + lq] = f2bf(od[r]);
  }
  if (lq == 0) {
#pragma unroll
    for (int r = 0; r < 4; ++r) {
      Pml[(pr0 + g * 4 + r) * 2] = Mx[r];
      Pml[(pr0 + g * 4 + r) * 2 + 1] = Lt[r];
    }
  }
}

// Merge two split-K halves -> normalized bf16 O [M x 384].
__global__ __launch_bounds__(256) void attn_merge(
    const ushort* __restrict__ Pacc, const float* __restrict__ Pml,
    ushort* __restrict__ Obf) {
  int idx = blockIdx.x * 256 + threadIdx.x;   // 32768 = M*H
  int h = idx & 7, bn = idx >> 3;
  int b = bn >> 11, n = bn & 2047;
  size_t r0 = ((size_t)(b * H + h)) * N + n;            // half 0
  size_t r1 = ((size_t)((B + b) * H + h)) * N + n;      // half 1
  float m0 = Pml[r0 * 2], l0 = Pml[r0 * 2 + 1];
  float m1 = Pml[r1 * 2], l1 = Pml[r1 * 2 + 1];
  float mm = fmaxf(m0, m1);
  float w0 = EXP2(m0 - mm), w1 = EXP2(m1 - mm);
  float inv = 1.f / (l0 * w0 + l1 * w1);
  w0 *= inv; w1 *= inv;
  const ushort* p0 = Pacc + r0 * 48;
  const ushort* p1 = Pacc + r1 * 48;
  ushort* ob = Obf + (size_t)bn * 384 + h * 48;
#pragma unroll
  for (int j = 0; j < 6; ++j) {
    uint4 a = *(const uint4*)(p0 + j * 8);
    uint4 c = *(const uint4*)(p1 + j * 8);
    uint4 o;
    o.x = pk_bf16(bf2f((ushort)a.x) * w0 + bf2f((ushort)c.x) * w1,
                  bf2f((ushort)(a.x >> 16)) * w0 + bf2f((ushort)(c.x >> 16)) * w1);
    o.y = pk_bf16(bf2f((ushort)a.y) * w0 + bf2f((ushort)c.y) * w1,
                  bf2f((ushort)(a.y >> 16)) * w0 + bf2f((ushort)(c.y >> 16)) * w1);
    o.z = pk_bf16(bf2f((ushort)a.z) * w0 + bf2f((ushort)c.z) * w1,
                  bf2f((ushort)(a.z >> 16)) * w0 + bf2f((ushort)(c.z >> 16)) * w1);
    o.w = pk_bf16(bf2f((ushort)a.w) * w0 + bf2f((ushort)c.w) * w1,
                  bf2f((ushort)(a.w >> 16)) * w0 + bf2f((ushort)(c.w >> 16)) * w1);
    *(uint4*)(ob + j * 8) = o;
  }
}

// Fused out-proj + residual + LayerNorm. Block = 64 rows x all 384 cols.
__global__ __launch_bounds__(256) void gemm_out_ln(
    const ushort* __restrict__ Abf, const ushort* __restrict__ Wbf,
    const float* __restrict__ x, const float* __restrict__ bo,
    const float* __restrict__ gamma, const float* __restrict__ beta,
    float* __restrict__ out) {
  __shared__ ushort Asm[64 * 32];    // 4KB
  __shared__ ushort Bsm[384 * 32];   // 24KB
  const int tid = threadIdx.x, w = tid >> 6, lane = tid & 63;
  const int lq = lane & 15, g = lane >> 4;
  const int brow = blockIdx.x * 64;
  const int srow = lane >> 2, scol = (lane & 3) * 8;
  f32x4 acc[24];
#pragma unroll
  for (int ni = 0; ni < 24; ++ni) acc[ni] = f32x4{0.f, 0.f, 0.f, 0.f};

  for (int kt = 0; kt < 384; kt += 32) {
    __syncthreads();
    gload16(Abf + (size_t)(brow + w * 16 + srow) * 384 + kt + scol, Asm + w * 512);
#pragma unroll
    for (int i = 0; i < 6; ++i) {
      int seg = w * 6 + i;
      gload16(Wbf + (size_t)(seg * 16 + srow) * 384 + kt + scol, Bsm + seg * 512);
    }
    __syncthreads();
    bf16x8 a = *(const bf16x8*)(Asm + (w * 16 + lq) * 32 + g * 8);
#pragma unroll
    for (int ni = 0; ni < 24; ++ni) {
      bf16x8 bfr = *(const bf16x8*)(Bsm + (ni * 16 + lq) * 32 + g * 8);
      acc[ni] = __builtin_amdgcn_mfma_f32_16x16x32_bf16(a, bfr, acc[ni], 0, 0, 0);
    }
  }

  const int row0 = brow + w * 16 + g * 4;
#pragma unroll
  for (int r = 0; r < 4; ++r) {
    const float* xr = x + (size_t)(row0 + r) * 384;
    float s = 0.f, s2 = 0.f;
#pragma unroll
    for (int ni = 0; ni < 24; ++ni) {
      int col = ni * 16 + lq;
      float y = acc[ni][r] + xr[col] + bo[col];
      acc[ni][r] = y;
      s += y; s2 += y * y;
    }
#pragma unroll
    for (int o = 1; o < 16; o <<= 1) {
      s += __shfl_xor(s, o);
      s2 += __shfl_xor(s2, o);
    }
    float mu = s * (1.f / 384.f);
    float var = s2 * (1.f / 384.f) - mu * mu;
    float rstd = rsqrtf(var + EPS);
    float* orow = out + (size_t)(row0 + r) * 384;
#pragma unroll
    for (int ni = 0; ni < 24; ++ni) {
      int col = ni * 16 + lq;
      orow[col] = (acc[ni][r] - mu) * rstd * gamma[col] + beta[col];
    }
  }
}

extern "C" void kernel_launch(void* const* d_in, const int* in_sizes, int n_in,
                              void* d_out, int out_size, void* d_ws, size_t ws_size,
                              hipStream_t stream) {
  const float* x      = (const float*)d_in[0];
  const float* frames = (const float*)d_in[1];
  const float* Wq     = (const float*)d_in[2];
  const float* Wk     = (const float*)d_in[3];
  const float* Wv     = (const float*)d_in[4];
  const float* Wo     = (const float*)d_in[5];
  const float* bo     = (const float*)d_in[6];
  const float* gamma  = (const float*)d_in[7];
  const float* beta   = (const float*)d_in[8];
  float* out = (float*)d_out;

  ushort* xbf  = (ushort*)d_ws;                 // M*384 (dead after gemm_qkv)
  ushort* Obf  = xbf;                           // alias: merged attn output
  ushort* Wqkv = xbf + (size_t)M * 384;         // 3*WSZ
  ushort* Wobf = Wqkv + 3 * (size_t)WSZ;        // WSZ
  ushort* Qpad = Wobf + (size_t)WSZ;            // M*512
  ushort* Kpad = Qpad + (size_t)M * 512;        // M*512
  ushort* Vt   = Kpad + (size_t)M * 512;        // M*384
  ushort* Pacc = Vt + (size_t)M * 384;          // 2*B*H*N*48 bf16 (6.3MB)
  float*  Pml  = (float*)(Pacc + (size_t)2 * B * H * N * 48);  // 2*B*H*N*2 f32

  // 1/sqrt(48) * log2(e): fold softmax scale + exp2 conversion into Q
  const float qscale = 0.14433756729740643f * 1.4426950408889634f;

  pack_all<<<(M * 384 + 4 * WSZ) / (8 * 256), 256, 0, stream>>>(
      x, Wq, Wk, Wv, Wo, xbf, Wqkv, Wobf);

  gemm_qkv<<<dim3(9, 64), 256, 0, stream>>>(xbf, Wqkv, Qpad, Kpad, Vt);

  rotate_both<<<2 * M * H * 16 / 256, 256, 0, stream>>>(Qpad, Kpad, frames, qscale);

  attn_mfma<<<2 * B * H * (N / 64), 256, 0, stream>>>(Qpad, Kpad, Vt, Pacc, Pml);

  attn_merge<<<M * H / 256, 256, 0, stream>>>(Pacc, Pml, Obf);

  gemm_out_ln<<<M / 64, 256, 0, stream>>>(Obf, Wobf, x, bo, gamma, beta, out);
}

// Round 8
// 78.417 us; speedup vs baseline: 1.2890x; 1.2890x over previous
//
#include <hip/hip_runtime.h>
#include <hip/hip_bf16.h>
#include <math.h>

constexpr int B = 2, N = 2048, D = 384, H = 8, Dh = 48;
constexpr int M = B * N;            // 4096 rows
constexpr float EPS = 1e-5f;
constexpr int WSZ = 384 * 384;

typedef short bf16x8 __attribute__((ext_vector_type(8)));
typedef float f32x4 __attribute__((ext_vector_type(4)));

#if __has_builtin(__builtin_amdgcn_exp2f)
#define EXP2(x) __builtin_amdgcn_exp2f(x)
#else
#define EXP2(x) exp2f(x)
#endif

__device__ __forceinline__ ushort f2bf(float f) {
  union { float f; uint u; } v; v.f = f;
  uint r = v.u + 0x7fffu + ((v.u >> 16) & 1u);   // RNE
  return (ushort)(r >> 16);
}
__device__ __forceinline__ float bf2f(ushort u) {
  union { uint u; float f; } v; v.u = ((uint)u) << 16;
  return v.f;
}
// two f32 -> packed 2xbf16 (compiler emits v_cvt_pk_bf16_f32)
__device__ __forceinline__ uint pk_bf16(float lo, float hi) {
  union { __hip_bfloat162 h; uint u; } v;
  v.h = __float22bfloat162_rn(make_float2(lo, hi));
  return v.u;
}

// async 16B global->LDS (dest: wave-uniform base + lane*16; src: per-lane)
__device__ __forceinline__ void gload16(const void* g, void* lds) {
  __builtin_amdgcn_global_load_lds(
      (const __attribute__((address_space(1))) unsigned int*)g,
      (__attribute__((address_space(3))) unsigned int*)lds, 16, 0, 0);
}

// Pack x and all 4 weights to bf16 in one kernel. 8 f32 per thread.
__global__ __launch_bounds__(256) void pack_all(
    const float* __restrict__ x, const float* __restrict__ Wq,
    const float* __restrict__ Wk, const float* __restrict__ Wv,
    const float* __restrict__ Wo, ushort* __restrict__ xbf,
    ushort* __restrict__ Wqkv, ushort* __restrict__ Wobf) {
  constexpr int XSZ = M * 384;
  int i = (blockIdx.x * 256 + threadIdx.x) * 8;
  const float* src; ushort* dst; int off;
  if (i < XSZ) { src = x; dst = xbf; off = i; }
  else {
    int j = i - XSZ;
    if (j < WSZ)          { src = Wq; dst = Wqkv;           off = j; }
    else if (j < 2 * WSZ) { src = Wk; dst = Wqkv + WSZ;     off = j - WSZ; }
    else if (j < 3 * WSZ) { src = Wv; dst = Wqkv + 2 * WSZ; off = j - 2 * WSZ; }
    else                  { src = Wo; dst = Wobf;           off = j - 3 * WSZ; }
  }
  float4 a = *(const float4*)(src + off);
  float4 b = *(const float4*)(src + off + 4);
  uint4 o;
  o.x = pk_bf16(a.x, a.y);
  o.y = pk_bf16(a.z, a.w);
  o.z = pk_bf16(b.x, b.y);
  o.w = pk_bf16(b.z, b.w);
  *(uint4*)(dst + off) = o;
}

// Fused QKV GEMM: [4096 x 1152] = xbf * Wqkv^T, bf16 MFMA, 64x128 tiles.
// Q cols -> Qpad[bn][h*64+dh], K cols -> Kpad (same layout), V -> Vt[b][h][dh][n].
__global__ __launch_bounds__(256) void gemm_qkv(
    const ushort* __restrict__ Abf, const ushort* __restrict__ Wbf,
    ushort* __restrict__ Qpad, ushort* __restrict__ Kpad,
    ushort* __restrict__ Vt) {
  __shared__ ushort Asm[64 * 32];
  __shared__ ushort Bsm[128 * 32];
  const int tid = threadIdx.x, w = tid >> 6, lane = tid & 63;
  const int lq = lane & 15, g = lane >> 4;
  const int brow = blockIdx.y * 64, bcol = blockIdx.x * 128;
  const int wr0 = (w >> 1) * 32, wc0 = (w & 1) * 64;
  const int srow = lane >> 2, scol = (lane & 3) * 8;
  f32x4 acc[2][4];
#pragma unroll
  for (int mi = 0; mi < 2; ++mi)
#pragma unroll
    for (int ni = 0; ni < 4; ++ni) acc[mi][ni] = f32x4{0.f, 0.f, 0.f, 0.f};

  for (int kt = 0; kt < 384; kt += 32) {
    __syncthreads();
    gload16(Abf + (size_t)(brow + w * 16 + srow) * 384 + kt + scol, Asm + w * 512);
#pragma unroll
    for (int i = 0; i < 2; ++i) {
      int seg = w * 2 + i;
      gload16(Wbf + (size_t)(bcol + seg * 16 + srow) * 384 + kt + scol, Bsm + seg * 512);
    }
    __syncthreads();
    bf16x8 a[2], b[4];
#pragma unroll
    for (int mi = 0; mi < 2; ++mi)
      a[mi] = *(const bf16x8*)(Asm + (wr0 + mi * 16 + lq) * 32 + g * 8);
#pragma unroll
    for (int ni = 0; ni < 4; ++ni)
      b[ni] = *(const bf16x8*)(Bsm + (wc0 + ni * 16 + lq) * 32 + g * 8);
#pragma unroll
    for (int mi = 0; mi < 2; ++mi)
#pragma unroll
      for (int ni = 0; ni < 4; ++ni)
        acc[mi][ni] = __builtin_amdgcn_mfma_f32_16x16x32_bf16(a[mi], b[ni], acc[mi][ni], 0, 0, 0);
  }

  if (bcol < 768) {
#pragma unroll
    for (int mi = 0; mi < 2; ++mi)
#pragma unroll
      for (int ni = 0; ni < 4; ++ni) {
        int colD = bcol + wc0 + ni * 16 + lq;
        ushort* dstm = (colD < 384) ? Qpad : Kpad;
        int c = (colD < 384) ? colD : colD - 384;
        int hh = c / 48, dh = c - hh * 48;
#pragma unroll
        for (int r = 0; r < 4; ++r) {
          int row = brow + wr0 + mi * 16 + g * 4 + r;
          dstm[(size_t)row * 512 + hh * 64 + dh] = f2bf(acc[mi][ni][r]);
        }
      }
  } else {
#pragma unroll
    for (int mi = 0; mi < 2; ++mi)
#pragma unroll
      for (int ni = 0; ni < 4; ++ni) {
        int vcol = bcol + wc0 + ni * 16 + lq - 768;
        int hh = vcol / 48, dh = vcol - hh * 48;
#pragma unroll
        for (int r = 0; r < 4; ++r) {
          int row = brow + wr0 + mi * 16 + g * 4 + r;
          int bb = row >> 11, nn = row & 2047;
          Vt[((size_t)(bb * H + hh) * 48 + dh) * N + nn] = f2bf(acc[mi][ni][r]);
        }
      }
  }
}

// In-place rotate 3-vector chunks of Qpad (scaled) and Kpad; zero pad halves 48..63.
__global__ __launch_bounds__(256) void rotate_both(
    ushort* __restrict__ Q, ushort* __restrict__ K,
    const float* __restrict__ F, float qscale) {
  constexpr int TOT = M * H * 16;
  int idx = blockIdx.x * 256 + threadIdx.x;   // 2*TOT threads
  ushort* T = (idx < TOT) ? Q : K;
  float scale = (idx < TOT) ? qscale : 1.0f;
  int rem = (idx < TOT) ? idx : idx - TOT;
  int gq = rem & 15;
  int nh = rem >> 4;
  int h = nh & 7;
  int bn = nh >> 3;
  ushort* p = T + (size_t)bn * 512 + h * 64;
  if (gq < 8) *(uint*)(p + 48 + gq * 2) = 0u;    // zero padding halves 48..63
  ushort* s = p + gq * 3;
  const float* R = F + (size_t)bn * 9;
  float v0 = bf2f(s[0]), v1 = bf2f(s[1]), v2 = bf2f(s[2]);
  float w0 = (R[0] * v0 + R[1] * v1 + R[2] * v2) * scale;
  float w1 = (R[3] * v0 + R[4] * v1 + R[5] * v2) * scale;
  float w2 = (R[6] * v0 + R[7] * v1 + R[8] * v2) * scale;
  s[0] = f2bf(w0); s[1] = f2bf(w1); s[2] = f2bf(w2);
}

// Split-K MFMA flash attention, 2 waves x 32 q, P-in-register via permuted keys.
// Block = (half,b,h,qt): 64 q rows; K tile staged with bit-permuted key order
// (LDS row [t41 t40 g1 g0 r1 r0] <- global key [t41 g1 g0 t40 r1 r0]) so the
// QK^T C-fragment IS the PV A-fragment after in-lane cvt_pk (no P LDS, no shfl).
// Writes unnormalized bf16 acc + f32 (m,l) per q.
__global__ __launch_bounds__(128) void attn_mfma(
    const ushort* __restrict__ Qpad, const ushort* __restrict__ Kpad,
    const ushort* __restrict__ Vt, ushort* __restrict__ Pacc,
    float* __restrict__ Pml) {
  __shared__ __align__(16) ushort SH[14336];   // 28KB
  ushort* K0 = SH;             // K dbuf: 2 x 64x64
  ushort* K1 = SH + 4096;
  ushort* V0 = SH + 8192;      // V dbuf: 2 x 48x64
  ushort* V1 = SH + 11264;

  const int bid = blockIdx.x;
  const int wg = (bid & 7) * 128 + (bid >> 3);  // XCD swizzle (1024 = 8*128)
  const int qt = wg & 31;
  const int rest = wg >> 5;
  const int h = rest & 7;
  const int b = (rest >> 3) & 1;
  const int half = rest >> 4;
  const int kt0 = half * 1024;
  const int tid = threadIdx.x;
  const int w = tid >> 6;        // 0..1
  const int lane = tid & 63;
  const int lq = lane & 15;
  const int g = lane >> 4;
  const int l7 = lq & 7;
  const int srow8 = lane >> 3;   // staging row within 8-row segment
  const int c8 = (lane & 7) ^ srow8;  // inverse-swizzled source chunk

  // Q frags: wave w owns q-groups 2w, 2w+1 (32 q)
  bf16x8 qf[2][2];
  {
    const ushort* qb = Qpad + ((size_t)(b * N) + qt * 64 + w * 32) * 512 + h * 64;
#pragma unroll
    for (int i = 0; i < 2; ++i)
#pragma unroll
      for (int kd = 0; kd < 2; ++kd)
        qf[i][kd] = *(const bf16x8*)(qb + (size_t)(i * 16 + lq) * 512 + kd * 32 + g * 8);
  }

  // K staging: segs s = w+2j; LDS row rho = s*8+srow8 holds global key kt+kappa(rho)
  const ushort* kg[4];
#pragma unroll
  for (int j = 0; j < 4; ++j) {
    int s = w + 2 * j;
    int kappa = (s >> 2) * 32 + (s & 1) * 16 + (srow8 >> 2) * 8 + ((s >> 1) & 1) * 4 + (srow8 & 3);
    kg[j] = Kpad + ((size_t)(b * N) + kt0 + kappa) * 512 + h * 64 + c8 * 8;
  }
  // V staging: segs sv = w+2j (j=0..2); rows = dh, keys linear (kappa indexes V cols)
  const ushort* vg[3];
#pragma unroll
  for (int j = 0; j < 3; ++j) {
    int sv = w + 2 * j;
    vg[j] = Vt + ((size_t)(b * H + h) * 48 + sv * 8 + srow8) * (size_t)N + kt0 + c8 * 8;
  }

  auto stage = [&](ushort* kb, ushort* vb) {
#pragma unroll
    for (int j = 0; j < 4; ++j) {
      gload16(kg[j], kb + (w + 2 * j) * 512);
      kg[j] += 64 * 512;
    }
#pragma unroll
    for (int j = 0; j < 3; ++j) {
      gload16(vg[j], vb + (w + 2 * j) * 512);
      vg[j] += 64;
    }
  };

  float m[2] = {-3.0e38f, -3.0e38f}, l[2] = {0.f, 0.f};
  f32x4 oacc[2][3];
#pragma unroll
  for (int i = 0; i < 2; ++i)
#pragma unroll
    for (int d = 0; d < 3; ++d) oacc[i][d] = f32x4{0.f, 0.f, 0.f, 0.f};

  stage(K0, V0);
  __syncthreads();
  int cur = 0;

  for (int t = 0; t < 16; ++t) {
    if (t < 15) stage(cur ? K0 : K1, cur ? V0 : V1);
    const ushort* Kc = cur ? K1 : K0;
    const ushort* Vc = cur ? V1 : V0;

    // S^T: st[i][t4][r] = S[LDS key row t4*16+g*4+r][q=(2w+i)*16+lq]
    f32x4 st[2][4];
#pragma unroll
    for (int i = 0; i < 2; ++i)
#pragma unroll
      for (int t4 = 0; t4 < 4; ++t4) st[i][t4] = f32x4{0.f, 0.f, 0.f, 0.f};
#pragma unroll
    for (int t4 = 0; t4 < 4; ++t4) {
      bf16x8 a0 = *(const bf16x8*)(Kc + (t4 * 16 + lq) * 64 + ((g ^ l7) * 8));
      bf16x8 a1 = *(const bf16x8*)(Kc + (t4 * 16 + lq) * 64 + (((g + 4) ^ l7) * 8));
#pragma unroll
      for (int i = 0; i < 2; ++i) {
        st[i][t4] = __builtin_amdgcn_mfma_f32_16x16x32_bf16(a0, qf[i][0], st[i][t4], 0, 0, 0);
        st[i][t4] = __builtin_amdgcn_mfma_f32_16x16x32_bf16(a1, qf[i][1], st[i][t4], 0, 0, 0);
      }
    }

    // V frags (shared across both q-groups)
    bf16x8 vf[2][3];
#pragma unroll
    for (int ks = 0; ks < 2; ++ks)
#pragma unroll
      for (int d = 0; d < 3; ++d)
        vf[ks][d] = *(const bf16x8*)(Vc + (d * 16 + lq) * 64 + ((((ks << 2) | g) ^ l7) * 8));

    // online softmax (defer-max)
    float tmax[2];
#pragma unroll
    for (int i = 0; i < 2; ++i) {
      float t0 = st[i][0][0];
#pragma unroll
      for (int t4 = 0; t4 < 4; ++t4)
#pragma unroll
        for (int r = 0; r < 4; ++r) t0 = fmaxf(t0, st[i][t4][r]);
      t0 = fmaxf(t0, __shfl_xor(t0, 16));
      t0 = fmaxf(t0, __shfl_xor(t0, 32));
      tmax[i] = t0;
    }
    bool need = (tmax[0] > m[0] + 8.0f) | (tmax[1] > m[1] + 8.0f);
    if (__ballot(need)) {
#pragma unroll
      for (int i = 0; i < 2; ++i) {
        float mnew = fmaxf(m[i], tmax[i]);
        float corr = EXP2(m[i] - mnew);
        m[i] = mnew;
        l[i] *= corr;
#pragma unroll
        for (int r = 0; r < 4; ++r) {
          float cr = __shfl(corr, g * 4 + r);
#pragma unroll
          for (int d = 0; d < 3; ++d) oacc[i][d][r] *= cr;
        }
      }
    }

    // exp + in-lane pack to PV A-frags (permuted keys make layouts coincide)
    bf16x8 pf[2][2];
#pragma unroll
    for (int i = 0; i < 2; ++i) {
      float ps = 0.f;
      uint u0[4], u1[4];
#pragma unroll
      for (int t4 = 0; t4 < 4; ++t4) {
        float p0 = EXP2(st[i][t4][0] - m[i]);
        float p1 = EXP2(st[i][t4][1] - m[i]);
        float p2 = EXP2(st[i][t4][2] - m[i]);
        float p3 = EXP2(st[i][t4][3] - m[i]);
        ps += (p0 + p1) + (p2 + p3);
        if (t4 < 2) {
          u0[(t4 & 1) * 2]     = pk_bf16(p0, p1);
          u0[(t4 & 1) * 2 + 1] = pk_bf16(p2, p3);
        } else {
          u1[(t4 & 1) * 2]     = pk_bf16(p0, p1);
          u1[(t4 & 1) * 2 + 1] = pk_bf16(p2, p3);
        }
      }
      ps += __shfl_xor(ps, 16);
      ps += __shfl_xor(ps, 32);
      l[i] += ps;
      union { uint4 q; bf16x8 v; } c0, c1;
      c0.q = make_uint4(u0[0], u0[1], u0[2], u0[3]);
      c1.q = make_uint4(u1[0], u1[1], u1[2], u1[3]);
      pf[i][0] = c0.v;
      pf[i][1] = c1.v;
    }

    // PV: O[q][dh] += P * V
#pragma unroll
    for (int ks = 0; ks < 2; ++ks)
#pragma unroll
      for (int i = 0; i < 2; ++i)
#pragma unroll
        for (int d = 0; d < 3; ++d)
          oacc[i][d] = __builtin_amdgcn_mfma_f32_16x16x32_bf16(pf[i][ks], vf[ks][d], oacc[i][d], 0, 0, 0);

    __syncthreads();   // drains staged loads; guards dbuf reuse
    cur ^= 1;
  }

  // write unnormalized partials + (m,l); each wave owns its 32 q fully
#pragma unroll
  for (int i = 0; i < 2; ++i) {
    const size_t pr0 = ((size_t)((half * B + b) * H + h)) * N + qt * 64 + (w * 2 + i) * 16;
#pragma unroll
    for (int d = 0; d < 3; ++d)
#pragma unroll
      for (int r = 0; r < 4; ++r)
        Pacc[(pr0 + g * 4 + r) * 48 + d * 16 + lq] = f2bf(oacc[i][d][r]);
    if (g == 0) {
      Pml[(pr0 + lq) * 2] = m[i];
      Pml[(pr0 + lq) * 2 + 1] = l[i];
    }
  }
}

// Merge two split-K halves -> normalized bf16 O [M x 384].
__global__ __launch_bounds__(256) void attn_merge(
    const ushort* __restrict__ Pacc, const float* __restrict__ Pml,
    ushort* __restrict__ Obf) {
  int idx = blockIdx.x * 256 + threadIdx.x;   // 32768 = M*H
  int h = idx & 7, bn = idx >> 3;
  int b = bn >> 11, n = bn & 2047;
  size_t r0 = ((size_t)(b * H + h)) * N + n;            // half 0
  size_t r1 = ((size_t)((B + b) * H + h)) * N + n;      // half 1
  float m0 = Pml[r0 * 2], l0 = Pml[r0 * 2 + 1];
  float m1 = Pml[r1 * 2], l1 = Pml[r1 * 2 + 1];
  float mm = fmaxf(m0, m1);
  float w0 = EXP2(m0 - mm), w1 = EXP2(m1 - mm);
  float inv = 1.f / (l0 * w0 + l1 * w1);
  w0 *= inv; w1 *= inv;
  const ushort* p0 = Pacc + r0 * 48;
  const ushort* p1 = Pacc + r1 * 48;
  ushort* ob = Obf + (size_t)bn * 384 + h * 48;
#pragma unroll
  for (int j = 0; j < 6; ++j) {
    uint4 a = *(const uint4*)(p0 + j * 8);
    uint4 c = *(const uint4*)(p1 + j * 8);
    uint4 o;
    o.x = pk_bf16(bf2f((ushort)a.x) * w0 + bf2f((ushort)c.x) * w1,
                  bf2f((ushort)(a.x >> 16)) * w0 + bf2f((ushort)(c.x >> 16)) * w1);
    o.y = pk_bf16(bf2f((ushort)a.y) * w0 + bf2f((ushort)c.y) * w1,
                  bf2f((ushort)(a.y >> 16)) * w0 + bf2f((ushort)(c.y >> 16)) * w1);
    o.z = pk_bf16(bf2f((ushort)a.z) * w0 + bf2f((ushort)c.z) * w1,
                  bf2f((ushort)(a.z >> 16)) * w0 + bf2f((ushort)(c.z >> 16)) * w1);
    o.w = pk_bf16(bf2f((ushort)a.w) * w0 + bf2f((ushort)c.w) * w1,
                  bf2f((ushort)(a.w >> 16)) * w0 + bf2f((ushort)(c.w >> 16)) * w1);
    *(uint4*)(ob + j * 8) = o;
  }
}

// Fused out-proj + residual + LayerNorm. 16 rows/block, 256 blocks (1/CU).
__global__ __launch_bounds__(256) void gemm_out_ln(
    const ushort* __restrict__ Abf, const ushort* __restrict__ Wbf,
    const float* __restrict__ x, const float* __restrict__ bo,
    const float* __restrict__ gamma, const float* __restrict__ beta,
    float* __restrict__ out) {
  __shared__ ushort Asm[16 * 32];    // 1KB
  __shared__ ushort Bsm[384 * 32];   // 24KB
  __shared__ float red[4][16][2];
  const int tid = threadIdx.x, w = tid >> 6, lane = tid & 63;
  const int lq = lane & 15, g = lane >> 4;
  const int brow = blockIdx.x * 16;
  const int srow = lane >> 2, scol = (lane & 3) * 8;
  f32x4 acc[6];
#pragma unroll
  for (int ni = 0; ni < 6; ++ni) acc[ni] = f32x4{0.f, 0.f, 0.f, 0.f};

  for (int kt = 0; kt < 384; kt += 32) {
    __syncthreads();
    if (w == 0) gload16(Abf + (size_t)(brow + srow) * 384 + kt + scol, Asm);
#pragma unroll
    for (int i = 0; i < 6; ++i) {
      int seg = w * 6 + i;
      gload16(Wbf + (size_t)(seg * 16 + srow) * 384 + kt + scol, Bsm + seg * 512);
    }
    __syncthreads();
    bf16x8 a = *(const bf16x8*)(Asm + lq * 32 + g * 8);
#pragma unroll
    for (int ni = 0; ni < 6; ++ni) {
      bf16x8 bb = *(const bf16x8*)(Bsm + ((w * 6 + ni) * 16 + lq) * 32 + g * 8);
      acc[ni] = __builtin_amdgcn_mfma_f32_16x16x32_bf16(a, bb, acc[ni], 0, 0, 0);
    }
  }

  // y = O + x + bo; per-row partial sums (wave covers 96 cols)
  float s[4] = {0.f, 0.f, 0.f, 0.f}, s2[4] = {0.f, 0.f, 0.f, 0.f};
#pragma unroll
  for (int ni = 0; ni < 6; ++ni) {
    int col = (w * 6 + ni) * 16 + lq;
    float bcol = bo[col];
#pragma unroll
    for (int r = 0; r < 4; ++r) {
      float y = acc[ni][r] + x[(size_t)(brow + g * 4 + r) * 384 + col] + bcol;
      acc[ni][r] = y;
      s[r] += y; s2[r] += y * y;
    }
  }
#pragma unroll
  for (int o = 1; o < 16; o <<= 1) {
#pragma unroll
    for (int r = 0; r < 4; ++r) {
      s[r] += __shfl_xor(s[r], o);
      s2[r] += __shfl_xor(s2[r], o);
    }
  }
  if (lq == 0) {
#pragma unroll
    for (int r = 0; r < 4; ++r) {
      red[w][g * 4 + r][0] = s[r];
      red[w][g * 4 + r][1] = s2[r];
    }
  }
  __syncthreads();
#pragma unroll
  for (int r = 0; r < 4; ++r) {
    int row = g * 4 + r;
    float ts  = red[0][row][0] + red[1][row][0] + red[2][row][0] + red[3][row][0];
    float ts2 = red[0][row][1] + red[1][row][1] + red[2][row][1] + red[3][row][1];
    float mu = ts * (1.f / 384.f);
    float var = ts2 * (1.f / 384.f) - mu * mu;
    float rstd = rsqrtf(var + EPS);
    float* orow = out + (size_t)(brow + row) * 384;
#pragma unroll
    for (int ni = 0; ni < 6; ++ni) {
      int col = (w * 6 + ni) * 16 + lq;
      orow[col] = (acc[ni][r] - mu) * rstd * gamma[col] + beta[col];
    }
  }
}

extern "C" void kernel_launch(void* const* d_in, const int* in_sizes, int n_in,
                              void* d_out, int out_size, void* d_ws, size_t ws_size,
                              hipStream_t stream) {
  const float* x      = (const float*)d_in[0];
  const float* frames = (const float*)d_in[1];
  const float* Wq     = (const float*)d_in[2];
  const float* Wk     = (const float*)d_in[3];
  const float* Wv     = (const float*)d_in[4];
  const float* Wo     = (const float*)d_in[5];
  const float* bo     = (const float*)d_in[6];
  const float* gamma  = (const float*)d_in[7];
  const float* beta   = (const float*)d_in[8];
  float* out = (float*)d_out;

  ushort* xbf  = (ushort*)d_ws;                 // M*384 (dead after gemm_qkv)
  ushort* Obf  = xbf;                           // alias: merged attn output
  ushort* Wqkv = xbf + (size_t)M * 384;         // 3*WSZ
  ushort* Wobf = Wqkv + 3 * (size_t)WSZ;        // WSZ
  ushort* Qpad = Wobf + (size_t)WSZ;            // M*512
  ushort* Kpad = Qpad + (size_t)M * 512;        // M*512
  ushort* Vt   = Kpad + (size_t)M * 512;        // M*384
  ushort* Pacc = Vt + (size_t)M * 384;          // 2*B*H*N*48 bf16 (6.3MB)
  float*  Pml  = (float*)(Pacc + (size_t)2 * B * H * N * 48);  // 2*B*H*N*2 f32

  // 1/sqrt(48) * log2(e): fold softmax scale + exp2 conversion into Q
  const float qscale = 0.14433756729740643f * 1.4426950408889634f;

  pack_all<<<(M * 384 + 4 * WSZ) / (8 * 256), 256, 0, stream>>>(
      x, Wq, Wk, Wv, Wo, xbf, Wqkv, Wobf);

  gemm_qkv<<<dim3(9, 64), 256, 0, stream>>>(xbf, Wqkv, Qpad, Kpad, Vt);

  rotate_both<<<2 * M * H * 16 / 256, 256, 0, stream>>>(Qpad, Kpad, frames, qscale);

  attn_mfma<<<2 * B * H * (N / 64), 128, 0, stream>>>(Qpad, Kpad, Vt, Pacc, Pml);

  attn_merge<<<M * H / 256, 256, 0, stream>>>(Pacc, Pml, Obf);

  gemm_out_ln<<<M / 16, 256, 0, stream>>>(Obf, Wobf, x, bo, gamma, beta, out);
}

// Round 9
// 74.671 us; speedup vs baseline: 1.3537x; 1.0502x over previous
//
#include <hip/hip_runtime.h>
#include <hip/hip_bf16.h>
#include <math.h>

constexpr int B = 2, N = 2048, D = 384, H = 8, Dh = 48;
constexpr int M = B * N;            // 4096 rows
constexpr float EPS = 1e-5f;
constexpr int WSZ = 384 * 384;

typedef short bf16x8 __attribute__((ext_vector_type(8)));
typedef float f32x4 __attribute__((ext_vector_type(4)));

#if __has_builtin(__builtin_amdgcn_exp2f)
#define EXP2(x) __builtin_amdgcn_exp2f(x)
#else
#define EXP2(x) exp2f(x)
#endif

__device__ __forceinline__ ushort f2bf(float f) {
  union { float f; uint u; } v; v.f = f;
  uint r = v.u + 0x7fffu + ((v.u >> 16) & 1u);   // RNE
  return (ushort)(r >> 16);
}
__device__ __forceinline__ float bf2f(ushort u) {
  union { uint u; float f; } v; v.u = ((uint)u) << 16;
  return v.f;
}
// two f32 -> packed 2xbf16 (compiler emits v_cvt_pk_bf16_f32)
__device__ __forceinline__ uint pk_bf16(float lo, float hi) {
  union { __hip_bfloat162 h; uint u; } v;
  v.h = __float22bfloat162_rn(make_float2(lo, hi));
  return v.u;
}

// async 16B global->LDS (dest: wave-uniform base + lane*16; src: per-lane)
__device__ __forceinline__ void gload16(const void* g, void* lds) {
  __builtin_amdgcn_global_load_lds(
      (const __attribute__((address_space(1))) unsigned int*)g,
      (__attribute__((address_space(3))) unsigned int*)lds, 16, 0, 0);
}

// Pack x and all 4 weights to bf16 in one kernel. 8 f32 per thread.
__global__ __launch_bounds__(256) void pack_all(
    const float* __restrict__ x, const float* __restrict__ Wq,
    const float* __restrict__ Wk, const float* __restrict__ Wv,
    const float* __restrict__ Wo, ushort* __restrict__ xbf,
    ushort* __restrict__ Wqkv, ushort* __restrict__ Wobf) {
  constexpr int XSZ = M * 384;
  int i = (blockIdx.x * 256 + threadIdx.x) * 8;
  const float* src; ushort* dst; int off;
  if (i < XSZ) { src = x; dst = xbf; off = i; }
  else {
    int j = i - XSZ;
    if (j < WSZ)          { src = Wq; dst = Wqkv;           off = j; }
    else if (j < 2 * WSZ) { src = Wk; dst = Wqkv + WSZ;     off = j - WSZ; }
    else if (j < 3 * WSZ) { src = Wv; dst = Wqkv + 2 * WSZ; off = j - 2 * WSZ; }
    else                  { src = Wo; dst = Wobf;           off = j - 3 * WSZ; }
  }
  float4 a = *(const float4*)(src + off);
  float4 b = *(const float4*)(src + off + 4);
  uint4 o;
  o.x = pk_bf16(a.x, a.y);
  o.y = pk_bf16(a.z, a.w);
  o.z = pk_bf16(b.x, b.y);
  o.w = pk_bf16(b.z, b.w);
  *(uint4*)(dst + off) = o;
}

// Fused QKV GEMM: [4096 x 1152] = xbf * Wqkv^T, bf16 MFMA, 64x128 tiles.
// Q cols -> Qpad[bn][h*64+dh], K cols -> Kpad (same layout), V -> Vt[b][h][dh][n].
__global__ __launch_bounds__(256) void gemm_qkv(
    const ushort* __restrict__ Abf, const ushort* __restrict__ Wbf,
    ushort* __restrict__ Qpad, ushort* __restrict__ Kpad,
    ushort* __restrict__ Vt) {
  __shared__ ushort Asm[64 * 32];
  __shared__ ushort Bsm[128 * 32];
  const int tid = threadIdx.x, w = tid >> 6, lane = tid & 63;
  const int lq = lane & 15, g = lane >> 4;
  const int brow = blockIdx.y * 64, bcol = blockIdx.x * 128;
  const int wr0 = (w >> 1) * 32, wc0 = (w & 1) * 64;
  const int srow = lane >> 2, scol = (lane & 3) * 8;
  f32x4 acc[2][4];
#pragma unroll
  for (int mi = 0; mi < 2; ++mi)
#pragma unroll
    for (int ni = 0; ni < 4; ++ni) acc[mi][ni] = f32x4{0.f, 0.f, 0.f, 0.f};

  for (int kt = 0; kt < 384; kt += 32) {
    __syncthreads();
    gload16(Abf + (size_t)(brow + w * 16 + srow) * 384 + kt + scol, Asm + w * 512);
#pragma unroll
    for (int i = 0; i < 2; ++i) {
      int seg = w * 2 + i;
      gload16(Wbf + (size_t)(bcol + seg * 16 + srow) * 384 + kt + scol, Bsm + seg * 512);
    }
    __syncthreads();
    bf16x8 a[2], b[4];
#pragma unroll
    for (int mi = 0; mi < 2; ++mi)
      a[mi] = *(const bf16x8*)(Asm + (wr0 + mi * 16 + lq) * 32 + g * 8);
#pragma unroll
    for (int ni = 0; ni < 4; ++ni)
      b[ni] = *(const bf16x8*)(Bsm + (wc0 + ni * 16 + lq) * 32 + g * 8);
#pragma unroll
    for (int mi = 0; mi < 2; ++mi)
#pragma unroll
      for (int ni = 0; ni < 4; ++ni)
        acc[mi][ni] = __builtin_amdgcn_mfma_f32_16x16x32_bf16(a[mi], b[ni], acc[mi][ni], 0, 0, 0);
  }

  if (bcol < 768) {
#pragma unroll
    for (int mi = 0; mi < 2; ++mi)
#pragma unroll
      for (int ni = 0; ni < 4; ++ni) {
        int colD = bcol + wc0 + ni * 16 + lq;
        ushort* dstm = (colD < 384) ? Qpad : Kpad;
        int c = (colD < 384) ? colD : colD - 384;
        int hh = c / 48, dh = c - hh * 48;
#pragma unroll
        for (int r = 0; r < 4; ++r) {
          int row = brow + wr0 + mi * 16 + g * 4 + r;
          dstm[(size_t)row * 512 + hh * 64 + dh] = f2bf(acc[mi][ni][r]);
        }
      }
  } else {
#pragma unroll
    for (int mi = 0; mi < 2; ++mi)
#pragma unroll
      for (int ni = 0; ni < 4; ++ni) {
        int vcol = bcol + wc0 + ni * 16 + lq - 768;
        int hh = vcol / 48, dh = vcol - hh * 48;
#pragma unroll
        for (int r = 0; r < 4; ++r) {
          int row = brow + wr0 + mi * 16 + g * 4 + r;
          int bb = row >> 11, nn = row & 2047;
          Vt[((size_t)(bb * H + hh) * 48 + dh) * N + nn] = f2bf(acc[mi][ni][r]);
        }
      }
  }
}

// Vectorized in-place rotate: one thread per (matrix, node, head).
// 6x uint4 load, 16 3x3 rotations in registers, 6x uint4 store + 2x uint4 zero pad.
__global__ __launch_bounds__(256) void rotate_both(
    ushort* __restrict__ Q, ushort* __restrict__ K,
    const float* __restrict__ F, float qscale) {
  int idx = blockIdx.x * 256 + threadIdx.x;   // 2*M*H = 65536
  int h = idx & 7;
  int bn = (idx >> 3) & 4095;
  int mat = idx >> 15;                        // 0=Q, 1=K
  ushort* p = (mat ? K : Q) + (size_t)bn * 512 + h * 64;
  float scale = mat ? 1.0f : qscale;
  const float* R = F + (size_t)bn * 9;
  float r0 = R[0], r1 = R[1], r2 = R[2];
  float r3 = R[3], r4 = R[4], r5 = R[5];
  float r6 = R[6], r7 = R[7], r8 = R[8];
  uint u[24];
#pragma unroll
  for (int j = 0; j < 6; ++j)
    *(uint4*)(u + j * 4) = *(const uint4*)(p + j * 8);
  float f[48];
#pragma unroll
  for (int j = 0; j < 24; ++j) {
    f[2 * j] = bf2f((ushort)u[j]);
    f[2 * j + 1] = bf2f((ushort)(u[j] >> 16));
  }
  float o[48];
#pragma unroll
  for (int t = 0; t < 16; ++t) {
    float v0 = f[3 * t], v1 = f[3 * t + 1], v2 = f[3 * t + 2];
    o[3 * t]     = (r0 * v0 + r1 * v1 + r2 * v2) * scale;
    o[3 * t + 1] = (r3 * v0 + r4 * v1 + r5 * v2) * scale;
    o[3 * t + 2] = (r6 * v0 + r7 * v1 + r8 * v2) * scale;
  }
  uint ow[24];
#pragma unroll
  for (int j = 0; j < 24; ++j) ow[j] = pk_bf16(o[2 * j], o[2 * j + 1]);
#pragma unroll
  for (int j = 0; j < 6; ++j)
    *(uint4*)(p + j * 8) = *(uint4*)(ow + j * 4);
  uint4 z = make_uint4(0, 0, 0, 0);
  *(uint4*)(p + 48) = z;
  *(uint4*)(p + 56) = z;
}

// Split-K MFMA flash attention, 4 waves x 32 q (block = 128 q), 64-key tiles,
// P-in-register via permuted key staging (LDS key row rho holds global key
// kappa(rho): [t41 t40 g1 g0 r1 r0] <- [t41 g1 g0 t40 r1 r0]) so the QK^T
// C-fragment IS the PV A-fragment after in-lane cvt_pk. No P LDS, no shfl for P.
// Writes unnormalized bf16 acc + f32 (m,l) per q.
__global__ __launch_bounds__(256) void attn_mfma(
    const ushort* __restrict__ Qpad, const ushort* __restrict__ Kpad,
    const ushort* __restrict__ Vt, ushort* __restrict__ Pacc,
    float* __restrict__ Pml) {
  __shared__ __align__(16) ushort SH[14336];   // 28KB
  ushort* K0 = SH;             // K dbuf: 2 x 64x64
  ushort* K1 = SH + 4096;
  ushort* V0 = SH + 8192;      // V dbuf: 2 x 48x64
  ushort* V1 = SH + 11264;

  const int bid = blockIdx.x;
  const int wg = (bid & 7) * 64 + (bid >> 3);  // XCD swizzle (512 = 8*64)
  const int qt = wg & 15;
  const int rest = wg >> 4;
  const int h = rest & 7;
  const int b = (rest >> 3) & 1;
  const int half = rest >> 4;
  const int kt0 = half * 1024;
  const int tid = threadIdx.x;
  const int w = tid >> 6;        // 0..3
  const int lane = tid & 63;
  const int lq = lane & 15;
  const int g = lane >> 4;
  const int l7 = lq & 7;
  const int srow8 = lane >> 3;   // staging row within 8-row segment
  const int c8 = (lane & 7) ^ srow8;  // inverse-swizzled source chunk

  // Q frags: wave w owns q-groups (2w, 2w+1) => q = qt*128 + w*32 + i*16 + lq
  bf16x8 qf[2][2];
  {
    const ushort* qb = Qpad + ((size_t)(b * N) + qt * 128 + w * 32) * 512 + h * 64;
#pragma unroll
    for (int i = 0; i < 2; ++i)
#pragma unroll
      for (int kd = 0; kd < 2; ++kd)
        qf[i][kd] = *(const bf16x8*)(qb + (size_t)(i * 16 + lq) * 512 + kd * 32 + g * 8);
  }

  // K staging: wave w stages segs {w, w+4}; LDS row rho = s*8+srow8 holds kt+kappa
  const ushort* kg0;
  const ushort* kg1;
  {
    int s0 = w;
    int k0i = (s0 >> 2) * 32 + (s0 & 1) * 16 + (srow8 >> 2) * 8 + ((s0 >> 1) & 1) * 4 + (srow8 & 3);
    kg0 = Kpad + ((size_t)(b * N) + kt0 + k0i) * 512 + h * 64 + c8 * 8;
    int s1 = w + 4;
    int k1i = (s1 >> 2) * 32 + (s1 & 1) * 16 + (srow8 >> 2) * 8 + ((s1 >> 1) & 1) * 4 + (srow8 & 3);
    kg1 = Kpad + ((size_t)(b * N) + kt0 + k1i) * 512 + h * 64 + c8 * 8;
  }
  // V staging: wave w stages seg w; waves 0,1 also stage segs 4,5
  const ushort* vg0 = Vt + ((size_t)(b * H + h) * 48 + w * 8 + srow8) * (size_t)N + kt0 + c8 * 8;
  const ushort* vg1 = vg0 + 32 * (size_t)N;   // rows +32 (segs 4,5), only w<2

  auto stage = [&](ushort* kb, ushort* vb) {
    gload16(kg0, kb + w * 512);
    gload16(kg1, kb + (w + 4) * 512);
    gload16(vg0, vb + w * 512);
    if (w < 2) gload16(vg1, vb + (w + 4) * 512);
    kg0 += 64 * 512; kg1 += 64 * 512; vg0 += 64; vg1 += 64;
  };

  float m[2] = {-3.0e38f, -3.0e38f}, l[2] = {0.f, 0.f};
  f32x4 oacc[2][3];
#pragma unroll
  for (int i = 0; i < 2; ++i)
#pragma unroll
    for (int d = 0; d < 3; ++d) oacc[i][d] = f32x4{0.f, 0.f, 0.f, 0.f};

  stage(K0, V0);
  __syncthreads();
  int cur = 0;

  for (int t = 0; t < 16; ++t) {
    if (t < 15) stage(cur ? K0 : K1, cur ? V0 : V1);
    const ushort* Kc = cur ? K1 : K0;
    const ushort* Vc = cur ? V1 : V0;

    // S^T: st[i][t4][r] = S[LDS key row t4*16+g*4+r][q=(w*2+i)*16+lq]
    f32x4 st[2][4];
#pragma unroll
    for (int i = 0; i < 2; ++i)
#pragma unroll
      for (int t4 = 0; t4 < 4; ++t4) st[i][t4] = f32x4{0.f, 0.f, 0.f, 0.f};
#pragma unroll
    for (int t4 = 0; t4 < 4; ++t4) {
      bf16x8 a0 = *(const bf16x8*)(Kc + (t4 * 16 + lq) * 64 + ((g ^ l7) * 8));
      bf16x8 a1 = *(const bf16x8*)(Kc + (t4 * 16 + lq) * 64 + (((g + 4) ^ l7) * 8));
#pragma unroll
      for (int i = 0; i < 2; ++i) {
        st[i][t4] = __builtin_amdgcn_mfma_f32_16x16x32_bf16(a0, qf[i][0], st[i][t4], 0, 0, 0);
        st[i][t4] = __builtin_amdgcn_mfma_f32_16x16x32_bf16(a1, qf[i][1], st[i][t4], 0, 0, 0);
      }
    }

    // V frags (shared across both q-groups)
    bf16x8 vf[2][3];
#pragma unroll
    for (int ks = 0; ks < 2; ++ks)
#pragma unroll
      for (int d = 0; d < 3; ++d)
        vf[ks][d] = *(const bf16x8*)(Vc + (d * 16 + lq) * 64 + ((((ks << 2) | g) ^ l7) * 8));

    // online softmax (defer-max)
    float tmax[2];
#pragma unroll
    for (int i = 0; i < 2; ++i) {
      float t0 = st[i][0][0];
#pragma unroll
      for (int t4 = 0; t4 < 4; ++t4)
#pragma unroll
        for (int r = 0; r < 4; ++r) t0 = fmaxf(t0, st[i][t4][r]);
      t0 = fmaxf(t0, __shfl_xor(t0, 16));
      t0 = fmaxf(t0, __shfl_xor(t0, 32));
      tmax[i] = t0;
    }
    bool need = (tmax[0] > m[0] + 8.0f) | (tmax[1] > m[1] + 8.0f);
    if (__ballot(need)) {
#pragma unroll
      for (int i = 0; i < 2; ++i) {
        float mnew = fmaxf(m[i], tmax[i]);
        float corr = EXP2(m[i] - mnew);
        m[i] = mnew;
        l[i] *= corr;
#pragma unroll
        for (int r = 0; r < 4; ++r) {
          float cr = __shfl(corr, g * 4 + r);
#pragma unroll
          for (int d = 0; d < 3; ++d) oacc[i][d][r] *= cr;
        }
      }
    }

    // exp + in-lane pack to PV A-frags (permuted keys make layouts coincide)
    bf16x8 pf[2][2];
#pragma unroll
    for (int i = 0; i < 2; ++i) {
      float ps = 0.f;
      uint u0[4], u1[4];
#pragma unroll
      for (int t4 = 0; t4 < 4; ++t4) {
        float p0 = EXP2(st[i][t4][0] - m[i]);
        float p1 = EXP2(st[i][t4][1] - m[i]);
        float p2 = EXP2(st[i][t4][2] - m[i]);
        float p3 = EXP2(st[i][t4][3] - m[i]);
        ps += (p0 + p1) + (p2 + p3);
        if (t4 < 2) {
          u0[(t4 & 1) * 2]     = pk_bf16(p0, p1);
          u0[(t4 & 1) * 2 + 1] = pk_bf16(p2, p3);
        } else {
          u1[(t4 & 1) * 2]     = pk_bf16(p0, p1);
          u1[(t4 & 1) * 2 + 1] = pk_bf16(p2, p3);
        }
      }
      ps += __shfl_xor(ps, 16);
      ps += __shfl_xor(ps, 32);
      l[i] += ps;
      union { uint4 q; bf16x8 v; } c0, c1;
      c0.q = make_uint4(u0[0], u0[1], u0[2], u0[3]);
      c1.q = make_uint4(u1[0], u1[1], u1[2], u1[3]);
      pf[i][0] = c0.v;
      pf[i][1] = c1.v;
    }

    // PV: O[q][dh] += P * V
#pragma unroll
    for (int ks = 0; ks < 2; ++ks)
#pragma unroll
      for (int i = 0; i < 2; ++i)
#pragma unroll
        for (int d = 0; d < 3; ++d)
          oacc[i][d] = __builtin_amdgcn_mfma_f32_16x16x32_bf16(pf[i][ks], vf[ks][d], oacc[i][d], 0, 0, 0);

    __syncthreads();   // drains staged loads; guards dbuf reuse
    cur ^= 1;
  }

  // write unnormalized partials + (m,l); each wave owns its 32 q fully
#pragma unroll
  for (int i = 0; i < 2; ++i) {
    const size_t pr0 = ((size_t)((half * B + b) * H + h)) * N + qt * 128 + w * 32 + i * 16;
#pragma unroll
    for (int d = 0; d < 3; ++d)
#pragma unroll
      for (int r = 0; r < 4; ++r)
        Pacc[(pr0 + g * 4 + r) * 48 + d * 16 + lq] = f2bf(oacc[i][d][r]);
    if (g == 0) {
      Pml[(pr0 + lq) * 2] = m[i];
      Pml[(pr0 + lq) * 2 + 1] = l[i];
    }
  }
}

// Fused split-K merge + out-proj + residual + LayerNorm. 16 rows/block, 256 blocks.
__global__ __launch_bounds__(256) void gemm_out_ln(
    const ushort* __restrict__ Pacc, const float* __restrict__ Pml,
    const ushort* __restrict__ Wbf, const float* __restrict__ x,
    const float* __restrict__ bo, const float* __restrict__ gamma,
    const float* __restrict__ beta, float* __restrict__ out) {
  __shared__ ushort Asm[16 * 32];    // 1KB
  __shared__ ushort Bsm[384 * 32];   // 24KB
  __shared__ float red[4][16][2];
  __shared__ float Wm[16][8][2];     // merge weights per (row, head)
  const int tid = threadIdx.x, w = tid >> 6, lane = tid & 63;
  const int lq = lane & 15, g = lane >> 4;
  const int brow = blockIdx.x * 16;
  const int srow = lane >> 2, scol = (lane & 3) * 8;

  if (tid < 128) {   // split-K merge weights (normalized)
    int r = tid >> 3, hh = tid & 7;
    int gr = brow + r;
    int bb = gr >> 11, nn = gr & 2047;
    size_t i0 = ((size_t)(bb * H + hh)) * N + nn;
    size_t i1 = ((size_t)((B + bb) * H + hh)) * N + nn;
    float m0 = Pml[i0 * 2], l0 = Pml[i0 * 2 + 1];
    float m1 = Pml[i1 * 2], l1 = Pml[i1 * 2 + 1];
    float mm = fmaxf(m0, m1);
    float e0 = EXP2(m0 - mm), e1 = EXP2(m1 - mm);
    float inv = 1.f / (l0 * e0 + l1 * e1);
    Wm[r][hh][0] = e0 * inv;
    Wm[r][hh][1] = e1 * inv;
  }
  __syncthreads();

  f32x4 acc[6];
#pragma unroll
  for (int ni = 0; ni < 6; ++ni) acc[ni] = f32x4{0.f, 0.f, 0.f, 0.f};

  for (int kt = 0; kt < 384; kt += 32) {
    __syncthreads();
    if (w == 0) {   // A-staging with fused split-K merge (8-run stays in one head)
      int col = kt + scol;
      int hh = col / 48;
      int dcol = col - hh * 48;
      int gr = brow + srow;
      int bb = gr >> 11, nn = gr & 2047;
      const ushort* a0p = Pacc + (((size_t)(bb * H + hh)) * N + nn) * 48 + dcol;
      const ushort* a1p = Pacc + (((size_t)((B + bb) * H + hh)) * N + nn) * 48 + dcol;
      bf16x8 a0 = *(const bf16x8*)a0p;
      bf16x8 a1 = *(const bf16x8*)a1p;
      float w0v = Wm[srow][hh][0], w1v = Wm[srow][hh][1];
      uint mg[4];
#pragma unroll
      for (int j = 0; j < 4; ++j)
        mg[j] = pk_bf16(
            bf2f((ushort)a0[2 * j]) * w0v + bf2f((ushort)a1[2 * j]) * w1v,
            bf2f((ushort)a0[2 * j + 1]) * w0v + bf2f((ushort)a1[2 * j + 1]) * w1v);
      *(uint4*)(Asm + srow * 32 + scol) = make_uint4(mg[0], mg[1], mg[2], mg[3]);
    }
#pragma unroll
    for (int i = 0; i < 6; ++i) {
      int seg = w * 6 + i;
      gload16(Wbf + (size_t)(seg * 16 + srow) * 384 + kt + scol, Bsm + seg * 512);
    }
    __syncthreads();
    bf16x8 a = *(const bf16x8*)(Asm + lq * 32 + g * 8);
#pragma unroll
    for (int ni = 0; ni < 6; ++ni) {
      bf16x8 bb2 = *(const bf16x8*)(Bsm + ((w * 6 + ni) * 16 + lq) * 32 + g * 8);
      acc[ni] = __builtin_amdgcn_mfma_f32_16x16x32_bf16(a, bb2, acc[ni], 0, 0, 0);
    }
  }

  // y = O + x + bo; per-row partial sums (wave covers 96 cols)
  float s[4] = {0.f, 0.f, 0.f, 0.f}, s2[4] = {0.f, 0.f, 0.f, 0.f};
#pragma unroll
  for (int ni = 0; ni < 6; ++ni) {
    int col = (w * 6 + ni) * 16 + lq;
    float bcol = bo[col];
#pragma unroll
    for (int r = 0; r < 4; ++r) {
      float y = acc[ni][r] + x[(size_t)(brow + g * 4 + r) * 384 + col] + bcol;
      acc[ni][r] = y;
      s[r] += y; s2[r] += y * y;
    }
  }
#pragma unroll
  for (int o = 1; o < 16; o <<= 1) {
#pragma unroll
    for (int r = 0; r < 4; ++r) {
      s[r] += __shfl_xor(s[r], o);
      s2[r] += __shfl_xor(s2[r], o);
    }
  }
  if (lq == 0) {
#pragma unroll
    for (int r = 0; r < 4; ++r) {
      red[w][g * 4 + r][0] = s[r];
      red[w][g * 4 + r][1] = s2[r];
    }
  }
  __syncthreads();
#pragma unroll
  for (int r = 0; r < 4; ++r) {
    int row = g * 4 + r;
    float ts  = red[0][row][0] + red[1][row][0] + red[2][row][0] + red[3][row][0];
    float ts2 = red[0][row][1] + red[1][row][1] + red[2][row][1] + red[3][row][1];
    float mu = ts * (1.f / 384.f);
    float var = ts2 * (1.f / 384.f) - mu * mu;
    float rstd = rsqrtf(var + EPS);
    float* orow = out + (size_t)(brow + row) * 384;
#pragma unroll
    for (int ni = 0; ni < 6; ++ni) {
      int col = (w * 6 + ni) * 16 + lq;
      orow[col] = (acc[ni][r] - mu) * rstd * gamma[col] + beta[col];
    }
  }
}

extern "C" void kernel_launch(void* const* d_in, const int* in_sizes, int n_in,
                              void* d_out, int out_size, void* d_ws, size_t ws_size,
                              hipStream_t stream) {
  const float* x      = (const float*)d_in[0];
  const float* frames = (const float*)d_in[1];
  const float* Wq     = (const float*)d_in[2];
  const float* Wk     = (const float*)d_in[3];
  const float* Wv     = (const float*)d_in[4];
  const float* Wo     = (const float*)d_in[5];
  const float* bo     = (const float*)d_in[6];
  const float* gamma  = (const float*)d_in[7];
  const float* beta   = (const float*)d_in[8];
  float* out = (float*)d_out;

  ushort* xbf  = (ushort*)d_ws;                 // M*384 (dead after gemm_qkv)
  ushort* Wqkv = xbf + (size_t)M * 384;         // 3*WSZ
  ushort* Wobf = Wqkv + 3 * (size_t)WSZ;        // WSZ
  ushort* Qpad = Wobf + (size_t)WSZ;            // M*512
  ushort* Kpad = Qpad + (size_t)M * 512;        // M*512
  ushort* Vt   = Kpad + (size_t)M * 512;        // M*384
  ushort* Pacc = Vt + (size_t)M * 384;          // 2*B*H*N*48 bf16 (6.3MB)
  float*  Pml  = (float*)(Pacc + (size_t)2 * B * H * N * 48);  // 2*B*H*N*2 f32

  // 1/sqrt(48) * log2(e): fold softmax scale + exp2 conversion into Q
  const float qscale = 0.14433756729740643f * 1.4426950408889634f;

  pack_all<<<(M * 384 + 4 * WSZ) / (8 * 256), 256, 0, stream>>>(
      x, Wq, Wk, Wv, Wo, xbf, Wqkv, Wobf);

  gemm_qkv<<<dim3(9, 64), 256, 0, stream>>>(xbf, Wqkv, Qpad, Kpad, Vt);

  rotate_both<<<2 * M * H / 256, 256, 0, stream>>>(Qpad, Kpad, frames, qscale);

  attn_mfma<<<2 * B * H * (N / 128), 256, 0, stream>>>(Qpad, Kpad, Vt, Pacc, Pml);

  gemm_out_ln<<<M / 16, 256, 0, stream>>>(Pacc, Pml, Wobf, x, bo, gamma, beta, out);
}